// Round 1
// baseline (1751.854 us; speedup 1.0000x reference)
//
#include <hip/hip_runtime.h>

#define B_ 2
#define S_ 2048
#define E_ 4096
#define H_ 32
#define KV_ 8
#define D_ 128

typedef __bf16 v8bf __attribute__((ext_vector_type(8)));
typedef __bf16 v4bf __attribute__((ext_vector_type(4)));
typedef float  v4f  __attribute__((ext_vector_type(4)));

static __device__ __forceinline__ v4f mfma16(v8bf a, v8bf b, v4f c) {
    return __builtin_amdgcn_mfma_f32_16x16x32_bf16(a, b, c, 0, 0, 0);
}

// async global->LDS, 16B per lane; LDS dest = wave-uniform base + lane*16
static __device__ __forceinline__ void load_lds16(const void* g, void* l) {
    __builtin_amdgcn_global_load_lds(
        (const __attribute__((address_space(1))) void*)g,
        (__attribute__((address_space(3))) void*)l, 16, 0, 0);
}

// ---------------- cast fp32 -> bf16 (vectorized) ----------------
__global__ __launch_bounds__(256) void cast_f32_to_bf16(
        const float4* __restrict__ in, v4bf* __restrict__ out, int n4) {
    int i = blockIdx.x * blockDim.x + threadIdx.x;
    if (i >= n4) return;
    float4 v = in[i];
    v4bf o;
    o[0] = (__bf16)v.x; o[1] = (__bf16)v.y; o[2] = (__bf16)v.z; o[3] = (__bf16)v.w;
    out[i] = o;
}

// ---------------- in-place RoPE on bf16 (B,S,nh*128) ----------------
__global__ __launch_bounds__(256) void rope_inplace(
        __bf16* __restrict__ qk, const int* __restrict__ pos, int nh, int rowstride) {
    int idx = blockIdx.x * blockDim.x + threadIdx.x;
    int d = idx & 63;
    int t = idx >> 6;
    int h = t % nh;
    int bs = t / nh;
    if (bs >= B_ * S_) return;
    int s = bs & (S_ - 1);
    float p = (float)pos[s];
    // inv_freq = 500000^(-d/64)
    float inv = expf(-(float)d * (1.0f / 64.0f) * 13.122363377404329f);
    float ang = p * inv;
    float c = cosf(ang), sn = sinf(ang);
    size_t off = (size_t)bs * rowstride + (size_t)h * D_;
    float x1 = (float)qk[off + d];
    float x2 = (float)qk[off + d + 64];
    qk[off + d]      = (__bf16)(x1 * c - x2 * sn);
    qk[off + d + 64] = (__bf16)(x2 * c + x1 * sn);
}

// ---------------- GEMM: C[M,N] = A[M,K] * B[N,K]^T, bf16 in, fp32 acc --------
// EPI 0: fp32 row-major C.  EPI 1: bf16 row-major C.
// EPI 2: bf16 V^T: C[m=(b,s)][n=(kv,d)] -> vt[((b*KV+kv)*D + d)*S + s]
template <int EPI>
__global__ __launch_bounds__(256) void gemm_bt(
        const __bf16* __restrict__ A, const __bf16* __restrict__ Bm,
        void* __restrict__ Cv, int M, int N, int K) {
    __shared__ __bf16 As[128 * 32];  // [m][k] row-major, 64B rows
    __shared__ __bf16 Bs[128 * 32];  // [n][k]
    const int tid  = threadIdx.x;
    const int wave = tid >> 6;
    const int lane = tid & 63;
    const int bm = blockIdx.y * 128;
    const int bn = blockIdx.x * 128;
    const int wm = (wave & 1) * 64;
    const int wn = (wave >> 1) * 64;
    const int l15  = lane & 15;
    const int quad = lane >> 4;

    v4f acc[4][4] = {};

    const int lm = lane >> 2;        // 0..15
    const int lk = (lane & 3) * 8;   // 0,8,16,24

    for (int k0 = 0; k0 < K; k0 += 32) {
        // stage A/B tiles: group g = i*4+wave owns rows g*16..g*16+15,
        // LDS bytes [g*1024, g*1024+1024) = base + lane*16
        load_lds16(A  + (size_t)(bm +      wave * 16 + lm) * K + k0 + lk, (char*)As + (size_t)wave * 1024);
        load_lds16(A  + (size_t)(bm + 64 + wave * 16 + lm) * K + k0 + lk, (char*)As + (size_t)(4 + wave) * 1024);
        load_lds16(Bm + (size_t)(bn +      wave * 16 + lm) * K + k0 + lk, (char*)Bs + (size_t)wave * 1024);
        load_lds16(Bm + (size_t)(bn + 64 + wave * 16 + lm) * K + k0 + lk, (char*)Bs + (size_t)(4 + wave) * 1024);
        __syncthreads();

        v8bf af[4], bf[4];
        const int kq = quad * 8;
#pragma unroll
        for (int i = 0; i < 4; ++i)
            af[i] = *(const v8bf*)&As[(wm + i * 16 + l15) * 32 + kq];
#pragma unroll
        for (int j = 0; j < 4; ++j)
            bf[j] = *(const v8bf*)&Bs[(wn + j * 16 + l15) * 32 + kq];
#pragma unroll
        for (int i = 0; i < 4; ++i)
#pragma unroll
            for (int j = 0; j < 4; ++j)
                acc[i][j] = mfma16(af[i], bf[j], acc[i][j]);
        __syncthreads();
    }

    // epilogue: C/D layout col = lane&15, row = quad*4 + r  (m89/m91 verified)
#pragma unroll
    for (int i = 0; i < 4; ++i) {
#pragma unroll
        for (int j = 0; j < 4; ++j) {
#pragma unroll
            for (int r = 0; r < 4; ++r) {
                int row = bm + wm + i * 16 + quad * 4 + r;
                int col = bn + wn + j * 16 + l15;
                float val = acc[i][j][r];
                if (EPI == 0) {
                    ((float*)Cv)[(size_t)row * N + col] = val;
                } else if (EPI == 1) {
                    ((__bf16*)Cv)[(size_t)row * N + col] = (__bf16)val;
                } else {
                    int b  = row >> 11, s = row & (S_ - 1);
                    int kv = col >> 7,  d = col & (D_ - 1);
                    ((__bf16*)Cv)[((size_t)((b * KV_ + kv) * D_ + d)) * S_ + s] = (__bf16)val;
                }
            }
        }
    }
}

// ---------------- fused causal flash attention ----------------
// q: (B,S,E) bf16 roped; k: (B,S,KV*D) bf16 roped; vt: (B,KV,D,S) bf16
// out attn: (B,S,E) bf16.  1 wave = 16 queries; block = 4 waves = 64 queries.
__global__ __launch_bounds__(256) void attn_fused(
        const __bf16* __restrict__ q, const __bf16* __restrict__ k,
        const __bf16* __restrict__ vt, __bf16* __restrict__ attn) {
    __shared__ __bf16 P[4][16 * 32];  // per-wave P tile [16 q][32 keys]
    const int wave = threadIdx.x >> 6;
    const int lane = threadIdx.x & 63;
    const int bh = blockIdx.y;
    const int b = bh >> 5;       // H=32
    const int h = bh & 31;
    const int kvh = h >> 2;      // rep = H/KV = 4
    const int q0 = blockIdx.x * 64 + wave * 16;
    const int l15  = lane & 15;
    const int quad = lane >> 4;

    const __bf16* qbase = q  + (size_t)(b * S_) * E_ + (size_t)h * D_;
    const __bf16* kbase = k  + (size_t)(b * S_) * (KV_ * D_) + (size_t)kvh * D_;
    const __bf16* vbase = vt + (size_t)((b * KV_ + kvh) * D_) * S_;

    v8bf aq[4];
#pragma unroll
    for (int kc = 0; kc < 4; ++kc)
        aq[kc] = *(const v8bf*)(qbase + (size_t)(q0 + l15) * E_ + kc * 32 + quad * 8);

    v4f o[8] = {};
    float m_i[4], l_i[4];
#pragma unroll
    for (int r = 0; r < 4; ++r) { m_i[r] = -INFINITY; l_i[r] = 0.f; }

    const int lastkey = blockIdx.x * 64 + 63;   // block-uniform trip count
    const int ntiles = (lastkey >> 5) + 1;
    const int rowbase = q0 + quad * 4;
    const float scale = 0.08838834764831845f;   // 1/sqrt(128)

    for (int t = 0; t < ntiles; ++t) {
        const int n0 = t * 32;
        v4f s0 = {}, s1 = {};
#pragma unroll
        for (int kc = 0; kc < 4; ++kc) {
            v8bf b0 = *(const v8bf*)(kbase + (size_t)(n0 +      l15) * (KV_ * D_) + kc * 32 + quad * 8);
            v8bf b1 = *(const v8bf*)(kbase + (size_t)(n0 + 16 + l15) * (KV_ * D_) + kc * 32 + quad * 8);
            s0 = mfma16(aq[kc], b0, s0);
            s1 = mfma16(aq[kc], b1, s1);
        }
        float p0[4], p1[4], mloc[4];
#pragma unroll
        for (int r = 0; r < 4; ++r) {
            float v0 = s0[r] * scale;
            float v1 = s1[r] * scale;
            if (n0 +      l15 > rowbase + r) v0 = -INFINITY;
            if (n0 + 16 + l15 > rowbase + r) v1 = -INFINITY;
            p0[r] = v0; p1[r] = v1;
            mloc[r] = fmaxf(v0, v1);
        }
#pragma unroll
        for (int off = 1; off < 16; off <<= 1)
#pragma unroll
            for (int r = 0; r < 4; ++r)
                mloc[r] = fmaxf(mloc[r], __shfl_xor(mloc[r], off, 64));

        float alpha[4], psum[4];
#pragma unroll
        for (int r = 0; r < 4; ++r) {
            float mnew = fmaxf(m_i[r], mloc[r]);     // finite after tile 0
            alpha[r] = __expf(m_i[r] - mnew);        // exp(-inf)=0 first time
            m_i[r] = mnew;
            float e0 = __expf(p0[r] - mnew);
            float e1 = __expf(p1[r] - mnew);
            p0[r] = e0; p1[r] = e1;
            psum[r] = e0 + e1;
        }
#pragma unroll
        for (int off = 1; off < 16; off <<= 1)
#pragma unroll
            for (int r = 0; r < 4; ++r)
                psum[r] += __shfl_xor(psum[r], off, 64);
#pragma unroll
        for (int r = 0; r < 4; ++r)
            l_i[r] = l_i[r] * alpha[r] + psum[r];
#pragma unroll
        for (int c = 0; c < 8; ++c)
#pragma unroll
            for (int r = 0; r < 4; ++r)
                o[c][r] *= alpha[r];

        // P: C-layout -> LDS [row][col]
#pragma unroll
        for (int r = 0; r < 4; ++r) {
            P[wave][(quad * 4 + r) * 32 + l15]      = (__bf16)p0[r];
            P[wave][(quad * 4 + r) * 32 + 16 + l15] = (__bf16)p1[r];
        }
        __syncthreads();
        // re-read as A-fragment: A[m=lane&15][k=quad*8+j]
        v8bf ap = *(const v8bf*)&P[wave][l15 * 32 + quad * 8];
#pragma unroll
        for (int c = 0; c < 8; ++c) {
            v8bf vb = *(const v8bf*)(vbase + (size_t)(c * 16 + l15) * S_ + n0 + quad * 8);
            o[c] = mfma16(ap, vb, o[c]);
        }
        __syncthreads();
    }

    float linv[4];
#pragma unroll
    for (int r = 0; r < 4; ++r) linv[r] = 1.0f / l_i[r];
    __bf16* obase = attn + (size_t)(b * S_) * E_ + (size_t)h * D_;
#pragma unroll
    for (int c = 0; c < 8; ++c)
#pragma unroll
        for (int r = 0; r < 4; ++r)
            obase[(size_t)(q0 + quad * 4 + r) * E_ + c * 16 + l15] =
                (__bf16)(o[c][r] * linv[r]);
}

extern "C" void kernel_launch(void* const* d_in, const int* in_sizes, int n_in,
                              void* d_out, int out_size, void* d_ws, size_t ws_size,
                              hipStream_t stream) {
    (void)in_sizes; (void)n_in; (void)out_size; (void)ws_size;
    const float* x  = (const float*)d_in[0];
    const float* wq = (const float*)d_in[1];
    const float* wk = (const float*)d_in[2];
    const float* wv = (const float*)d_in[3];
    const float* wo = (const float*)d_in[4];
    const int*   pos = (const int*)d_in[5];
    float* out = (float*)d_out;

    char* ws = (char*)d_ws;
    size_t off = 0;
    auto alloc = [&](size_t bytes) {
        char* p = ws + off;
        off += (bytes + 255) & ~(size_t)255;
        return p;
    };
    __bf16* xb  = (__bf16*)alloc((size_t)B_ * S_ * E_ * 2);
    __bf16* wqb = (__bf16*)alloc((size_t)E_ * E_ * 2);
    __bf16* wkb = (__bf16*)alloc((size_t)KV_ * D_ * E_ * 2);
    __bf16* wvb = (__bf16*)alloc((size_t)KV_ * D_ * E_ * 2);
    __bf16* wob = (__bf16*)alloc((size_t)E_ * E_ * 2);
    __bf16* qb  = (__bf16*)alloc((size_t)B_ * S_ * E_ * 2);
    __bf16* kb  = (__bf16*)alloc((size_t)B_ * S_ * KV_ * D_ * 2);
    __bf16* vt  = (__bf16*)alloc((size_t)B_ * KV_ * D_ * S_ * 2);
    __bf16* at  = (__bf16*)alloc((size_t)B_ * S_ * E_ * 2);

    auto cast = [&](const float* in, __bf16* ob, size_t n) {
        int n4 = (int)(n / 4);
        cast_f32_to_bf16<<<(n4 + 255) / 256, 256, 0, stream>>>(
            (const float4*)in, (v4bf*)ob, n4);
    };
    cast(x,  xb,  (size_t)B_ * S_ * E_);
    cast(wq, wqb, (size_t)E_ * E_);
    cast(wk, wkb, (size_t)KV_ * D_ * E_);
    cast(wv, wvb, (size_t)KV_ * D_ * E_);
    cast(wo, wob, (size_t)E_ * E_);

    const int M = B_ * S_;
    gemm_bt<1><<<dim3(E_ / 128, M / 128), 256, 0, stream>>>(xb, wqb, qb, M, E_, E_);
    gemm_bt<1><<<dim3(KV_ * D_ / 128, M / 128), 256, 0, stream>>>(xb, wkb, kb, M, KV_ * D_, E_);
    gemm_bt<2><<<dim3(KV_ * D_ / 128, M / 128), 256, 0, stream>>>(xb, wvb, vt, M, KV_ * D_, E_);

    rope_inplace<<<(B_ * S_ * H_ * 64 + 255) / 256, 256, 0, stream>>>(qb, pos, H_, E_);
    rope_inplace<<<(B_ * S_ * KV_ * 64 + 255) / 256, 256, 0, stream>>>(kb, pos, KV_ * D_ / 128 * 0 + KV_, KV_ * D_);

    attn_fused<<<dim3(S_ / 64, B_ * H_), 256, 0, stream>>>(qb, kb, vt, at);

    gemm_bt<0><<<dim3(E_ / 128, M / 128), 256, 0, stream>>>(at, wob, out, M, E_, E_);
}

// Round 2
// 1690.192 us; speedup vs baseline: 1.0365x; 1.0365x over previous
//
#include <hip/hip_runtime.h>

#define B_ 2
#define S_ 2048
#define E_ 4096
#define H_ 32
#define KV_ 8
#define D_ 128

typedef __bf16 v8bf __attribute__((ext_vector_type(8)));
typedef __bf16 v4bf __attribute__((ext_vector_type(4)));
typedef float  v4f  __attribute__((ext_vector_type(4)));

static __device__ __forceinline__ v4f mfma16(v8bf a, v8bf b, v4f c) {
    return __builtin_amdgcn_mfma_f32_16x16x32_bf16(a, b, c, 0, 0, 0);
}

// async global->LDS, 16B per lane; LDS dest = wave-uniform base + lane*16
static __device__ __forceinline__ void load_lds16(const void* g, void* l) {
    __builtin_amdgcn_global_load_lds(
        (const __attribute__((address_space(1))) void*)g,
        (__attribute__((address_space(3))) void*)l, 16, 0, 0);
}

// ---------------- cast fp32 -> bf16 (vectorized) ----------------
__global__ __launch_bounds__(256) void cast_f32_to_bf16(
        const float4* __restrict__ in, v4bf* __restrict__ out, int n4) {
    int i = blockIdx.x * blockDim.x + threadIdx.x;
    if (i >= n4) return;
    float4 v = in[i];
    v4bf o;
    o[0] = (__bf16)v.x; o[1] = (__bf16)v.y; o[2] = (__bf16)v.z; o[3] = (__bf16)v.w;
    out[i] = o;
}

// ---------------- in-place RoPE on bf16 (B,S,nh*128) ----------------
__global__ __launch_bounds__(256) void rope_inplace(
        __bf16* __restrict__ qk, const int* __restrict__ pos, int nh, int rowstride) {
    int idx = blockIdx.x * blockDim.x + threadIdx.x;
    int d = idx & 63;
    int t = idx >> 6;
    int h = t % nh;
    int bs = t / nh;
    if (bs >= B_ * S_) return;
    int s = bs & (S_ - 1);
    float p = (float)pos[s];
    // inv_freq = 500000^(-d/64)
    float inv = expf(-(float)d * (1.0f / 64.0f) * 13.122363377404329f);
    float ang = p * inv;
    float c = cosf(ang), sn = sinf(ang);
    size_t off = (size_t)bs * rowstride + (size_t)h * D_;
    float x1 = (float)qk[off + d];
    float x2 = (float)qk[off + d + 64];
    qk[off + d]      = (__bf16)(x1 * c - x2 * sn);
    qk[off + d + 64] = (__bf16)(x2 * c + x1 * sn);
}

// ---------------- GEMM: C[M,N] = A[M,K] * B[N,K]^T, bf16 in, fp32 acc --------
// EPI 0: fp32 row-major C.  EPI 1: bf16 row-major C.
// EPI 2: fused KV epilogue: col<1024 -> bf16 row-major into Cv (ld=1024);
//        col>=1024 -> bf16 V^T into Cv2: vt[((b*KV+kv)*D+d)*S + s]
template <int EPI>
__global__ __launch_bounds__(256) void gemm_bt(
        const __bf16* __restrict__ A, const __bf16* __restrict__ Bm,
        void* __restrict__ Cv, void* __restrict__ Cv2, int M, int N, int K) {
    __shared__ __bf16 As[128 * 32];  // [m][k] row-major, 64B rows
    __shared__ __bf16 Bs[128 * 32];  // [n][k]
    const int tid  = threadIdx.x;
    const int wave = tid >> 6;
    const int lane = tid & 63;
    const int bm = blockIdx.y * 128;
    const int bn = blockIdx.x * 128;
    const int wm = (wave & 1) * 64;
    const int wn = (wave >> 1) * 64;
    const int l15  = lane & 15;
    const int quad = lane >> 4;

    v4f acc[4][4] = {};

    const int lm = lane >> 2;        // 0..15
    const int lk = (lane & 3) * 8;   // 0,8,16,24

    for (int k0 = 0; k0 < K; k0 += 32) {
        load_lds16(A  + (size_t)(bm +      wave * 16 + lm) * K + k0 + lk, (char*)As + (size_t)wave * 1024);
        load_lds16(A  + (size_t)(bm + 64 + wave * 16 + lm) * K + k0 + lk, (char*)As + (size_t)(4 + wave) * 1024);
        load_lds16(Bm + (size_t)(bn +      wave * 16 + lm) * K + k0 + lk, (char*)Bs + (size_t)wave * 1024);
        load_lds16(Bm + (size_t)(bn + 64 + wave * 16 + lm) * K + k0 + lk, (char*)Bs + (size_t)(4 + wave) * 1024);
        __syncthreads();

        v8bf af[4], bf[4];
        const int kq = quad * 8;
#pragma unroll
        for (int i = 0; i < 4; ++i)
            af[i] = *(const v8bf*)&As[(wm + i * 16 + l15) * 32 + kq];
#pragma unroll
        for (int j = 0; j < 4; ++j)
            bf[j] = *(const v8bf*)&Bs[(wn + j * 16 + l15) * 32 + kq];
#pragma unroll
        for (int i = 0; i < 4; ++i)
#pragma unroll
            for (int j = 0; j < 4; ++j)
                acc[i][j] = mfma16(af[i], bf[j], acc[i][j]);
        __syncthreads();
    }

    // epilogue: C/D layout col = lane&15, row = quad*4 + r  (m89/m91 verified)
#pragma unroll
    for (int i = 0; i < 4; ++i) {
#pragma unroll
        for (int j = 0; j < 4; ++j) {
#pragma unroll
            for (int r = 0; r < 4; ++r) {
                int row = bm + wm + i * 16 + quad * 4 + r;
                int col = bn + wn + j * 16 + l15;
                float val = acc[i][j][r];
                if (EPI == 0) {
                    ((float*)Cv)[(size_t)row * N + col] = val;
                } else if (EPI == 1) {
                    ((__bf16*)Cv)[(size_t)row * N + col] = (__bf16)val;
                } else {
                    if (col < 1024) {
                        ((__bf16*)Cv)[(size_t)row * 1024 + col] = (__bf16)val;
                    } else {
                        int cc = col - 1024;
                        int b  = row >> 11, s = row & (S_ - 1);
                        int kv = cc >> 7,  d = cc & (D_ - 1);
                        ((__bf16*)Cv2)[((size_t)((b * KV_ + kv) * D_ + d)) * S_ + s] = (__bf16)val;
                    }
                }
            }
        }
    }
}

// ---------------- fused causal flash attention ----------------
// q: (B,S,E) bf16 roped; k: (B,S,KV*D) bf16 roped; vt: (B,KV,D,S) bf16
// out attn: (B,S,E) bf16.  1 wave = 16 queries, fully independent (no barriers:
// the P transpose goes through a wave-private LDS slice; same-wave ds ordering
// via lgkmcnt).  64-key tiles.
__global__ __launch_bounds__(256) void attn_fused(
        const __bf16* __restrict__ q, const __bf16* __restrict__ k,
        const __bf16* __restrict__ vt, __bf16* __restrict__ attn) {
    __shared__ __bf16 P[4][16 * 64];  // per-wave P tile [16 q][64 keys]
    const int wave = threadIdx.x >> 6;
    const int lane = threadIdx.x & 63;
    const int bh = blockIdx.y;
    const int b = bh >> 5;       // H=32
    const int h = bh & 31;
    const int kvh = h >> 2;      // rep = H/KV = 4
    const int qblk = (int)gridDim.x - 1 - (int)blockIdx.x;  // long blocks first
    const int q0 = qblk * 64 + wave * 16;
    const int l15  = lane & 15;
    const int quad = lane >> 4;

    const __bf16* qbase = q  + (size_t)(b * S_) * E_ + (size_t)h * D_;
    const __bf16* kbase = k  + (size_t)(b * S_) * (KV_ * D_) + (size_t)kvh * D_;
    const __bf16* vbase = vt + (size_t)((b * KV_ + kvh) * D_) * S_;
    __bf16* Pw = &P[wave][0];

    v8bf aq[4];
#pragma unroll
    for (int kc = 0; kc < 4; ++kc)
        aq[kc] = *(const v8bf*)(qbase + (size_t)(q0 + l15) * E_ + kc * 32 + quad * 8);

    v4f o[8] = {};
    float m_i[4], l_i[4];
#pragma unroll
    for (int r = 0; r < 4; ++r) { m_i[r] = -INFINITY; l_i[r] = 0.f; }

    const int ntiles = (q0 + 15) / 64 + 1;     // per-wave trip count
    const int rowbase = q0 + quad * 4;
    const float scale = 0.08838834764831845f;  // 1/sqrt(128)

    for (int t = 0; t < ntiles; ++t) {
        const int n0 = t * 64;

        // ---- QK^T: 16 queries x 64 keys ----
        v4f s[4] = {};
#pragma unroll
        for (int kc = 0; kc < 4; ++kc) {
            v8bf kf[4];
#pragma unroll
            for (int j = 0; j < 4; ++j)
                kf[j] = *(const v8bf*)(kbase + (size_t)(n0 + j * 16 + l15) * (KV_ * D_) + kc * 32 + quad * 8);
#pragma unroll
            for (int j = 0; j < 4; ++j)
                s[j] = mfma16(aq[kc], kf[j], s[j]);
        }

        // ---- scale + (boundary-only) causal mask ----
        float e[4][4];
        if (n0 + 63 > q0) {           // wave-uniform
#pragma unroll
            for (int j = 0; j < 4; ++j)
#pragma unroll
                for (int r = 0; r < 4; ++r) {
                    float v = s[j][r] * scale;
                    if (n0 + j * 16 + l15 > rowbase + r) v = -INFINITY;
                    e[j][r] = v;
                }
        } else {
#pragma unroll
            for (int j = 0; j < 4; ++j)
#pragma unroll
                for (int r = 0; r < 4; ++r)
                    e[j][r] = s[j][r] * scale;
        }

        // ---- online softmax (per-row over 16 l15 lanes within each quad) ----
        float mloc[4];
#pragma unroll
        for (int r = 0; r < 4; ++r)
            mloc[r] = fmaxf(fmaxf(e[0][r], e[1][r]), fmaxf(e[2][r], e[3][r]));
#pragma unroll
        for (int off = 1; off < 16; off <<= 1)
#pragma unroll
            for (int r = 0; r < 4; ++r)
                mloc[r] = fmaxf(mloc[r], __shfl_xor(mloc[r], off, 64));

        float alpha[4], psum[4];
#pragma unroll
        for (int r = 0; r < 4; ++r) {
            float mnew = fmaxf(m_i[r], mloc[r]);
            alpha[r] = __expf(m_i[r] - mnew);   // exp(-inf)=0 on first tile
            m_i[r] = mnew;
#pragma unroll
            for (int j = 0; j < 4; ++j)
                e[j][r] = __expf(e[j][r] - mnew);
            psum[r] = (e[0][r] + e[1][r]) + (e[2][r] + e[3][r]);
        }
#pragma unroll
        for (int off = 1; off < 16; off <<= 1)
#pragma unroll
            for (int r = 0; r < 4; ++r)
                psum[r] += __shfl_xor(psum[r], off, 64);
#pragma unroll
        for (int r = 0; r < 4; ++r)
            l_i[r] = l_i[r] * alpha[r] + psum[r];
#pragma unroll
        for (int c = 0; c < 8; ++c)
#pragma unroll
            for (int r = 0; r < 4; ++r)
                o[c][r] *= alpha[r];

        // ---- P: C-layout -> wave-private LDS [16 rows][64 cols] ----
#pragma unroll
        for (int j = 0; j < 4; ++j)
#pragma unroll
            for (int r = 0; r < 4; ++r)
                Pw[(quad * 4 + r) * 64 + j * 16 + l15] = (__bf16)e[j][r];

        // re-read as A-fragment: A[m=l15][k=quad*8+i] per 32-key chunk
        v8bf ap0 = *(const v8bf*)&Pw[l15 * 64 + quad * 8];
        v8bf ap1 = *(const v8bf*)&Pw[l15 * 64 + 32 + quad * 8];

        // ---- PV: o[d-tile] += P * V^T ----
#pragma unroll
        for (int c = 0; c < 8; ++c) {
            const __bf16* vrow = vbase + (size_t)(c * 16 + l15) * S_ + n0 + quad * 8;
            v8bf v0 = *(const v8bf*)(vrow);
            v8bf v1 = *(const v8bf*)(vrow + 32);
            o[c] = mfma16(ap0, v0, o[c]);
            o[c] = mfma16(ap1, v1, o[c]);
        }
    }

    float linv[4];
#pragma unroll
    for (int r = 0; r < 4; ++r) linv[r] = 1.0f / l_i[r];
    __bf16* obase = attn + (size_t)(b * S_) * E_ + (size_t)h * D_;
#pragma unroll
    for (int c = 0; c < 8; ++c)
#pragma unroll
        for (int r = 0; r < 4; ++r)
            obase[(size_t)(q0 + quad * 4 + r) * E_ + c * 16 + l15] =
                (__bf16)(o[c][r] * linv[r]);
}

extern "C" void kernel_launch(void* const* d_in, const int* in_sizes, int n_in,
                              void* d_out, int out_size, void* d_ws, size_t ws_size,
                              hipStream_t stream) {
    (void)in_sizes; (void)n_in; (void)out_size; (void)ws_size;
    const float* x  = (const float*)d_in[0];
    const float* wq = (const float*)d_in[1];
    const float* wk = (const float*)d_in[2];
    const float* wv = (const float*)d_in[3];
    const float* wo = (const float*)d_in[4];
    const int*   pos = (const int*)d_in[5];
    float* out = (float*)d_out;

    char* ws = (char*)d_ws;
    size_t off = 0;
    auto alloc = [&](size_t bytes) {
        char* p = ws + off;
        off += (bytes + 255) & ~(size_t)255;
        return p;
    };
    __bf16* xb   = (__bf16*)alloc((size_t)B_ * S_ * E_ * 2);
    __bf16* wqb  = (__bf16*)alloc((size_t)E_ * E_ * 2);
    __bf16* wkvb = (__bf16*)alloc((size_t)2 * KV_ * D_ * E_ * 2);  // [wk;wv] rows
    __bf16* wob  = (__bf16*)alloc((size_t)E_ * E_ * 2);
    __bf16* qb   = (__bf16*)alloc((size_t)B_ * S_ * E_ * 2);
    __bf16* kb   = (__bf16*)alloc((size_t)B_ * S_ * KV_ * D_ * 2);
    __bf16* vt   = (__bf16*)alloc((size_t)B_ * KV_ * D_ * S_ * 2);
    __bf16* at   = (__bf16*)alloc((size_t)B_ * S_ * E_ * 2);

    auto cast = [&](const float* in, __bf16* ob, size_t n) {
        int n4 = (int)(n / 4);
        cast_f32_to_bf16<<<(n4 + 255) / 256, 256, 0, stream>>>(
            (const float4*)in, (v4bf*)ob, n4);
    };
    cast(x,  xb,  (size_t)B_ * S_ * E_);
    cast(wq, wqb, (size_t)E_ * E_);
    cast(wk, wkvb, (size_t)KV_ * D_ * E_);
    cast(wv, wkvb + (size_t)KV_ * D_ * E_, (size_t)KV_ * D_ * E_);
    cast(wo, wob, (size_t)E_ * E_);

    const int M = B_ * S_;
    gemm_bt<1><<<dim3(E_ / 128, M / 128), 256, 0, stream>>>(
        xb, wqb, qb, nullptr, M, E_, E_);
    gemm_bt<2><<<dim3(2 * KV_ * D_ / 128, M / 128), 256, 0, stream>>>(
        xb, wkvb, kb, vt, M, 2 * KV_ * D_, E_);

    rope_inplace<<<(B_ * S_ * H_ * 64 + 255) / 256, 256, 0, stream>>>(qb, pos, H_, E_);
    rope_inplace<<<(B_ * S_ * KV_ * 64 + 255) / 256, 256, 0, stream>>>(kb, pos, KV_, KV_ * D_);

    attn_fused<<<dim3(S_ / 64, B_ * H_), 256, 0, stream>>>(qb, kb, vt, at);

    gemm_bt<0><<<dim3(E_ / 128, M / 128), 256, 0, stream>>>(
        at, wob, out, nullptr, M, E_, E_);
}

// Round 3
// 1064.876 us; speedup vs baseline: 1.6451x; 1.5872x over previous
//
#include <hip/hip_runtime.h>

#define B_ 2
#define S_ 2048
#define E_ 4096
#define H_ 32
#define KV_ 8
#define D_ 128

typedef __bf16 v8bf __attribute__((ext_vector_type(8)));
typedef __bf16 v4bf __attribute__((ext_vector_type(4)));
typedef float  v4f  __attribute__((ext_vector_type(4)));

static __device__ __forceinline__ v4f mfma16(v8bf a, v8bf b, v4f c) {
    return __builtin_amdgcn_mfma_f32_16x16x32_bf16(a, b, c, 0, 0, 0);
}

// async global->LDS, 16B per lane; LDS dest = wave-uniform base + lane*16
static __device__ __forceinline__ void load_lds16(const void* g, void* l) {
    __builtin_amdgcn_global_load_lds(
        (const __attribute__((address_space(1))) void*)g,
        (__attribute__((address_space(3))) void*)l, 16, 0, 0);
}

// ---------------- cast fp32 -> bf16 (vectorized) ----------------
__global__ __launch_bounds__(256) void cast_f32_to_bf16(
        const float4* __restrict__ in, v4bf* __restrict__ out, int n4) {
    int i = blockIdx.x * blockDim.x + threadIdx.x;
    if (i >= n4) return;
    float4 v = in[i];
    v4bf o;
    o[0] = (__bf16)v.x; o[1] = (__bf16)v.y; o[2] = (__bf16)v.z; o[3] = (__bf16)v.w;
    out[i] = o;
}

// ---------------- in-place RoPE on bf16 (B,S,nh*128) ----------------
__global__ __launch_bounds__(256) void rope_inplace(
        __bf16* __restrict__ qk, const int* __restrict__ pos, int nh, int rowstride) {
    int idx = blockIdx.x * blockDim.x + threadIdx.x;
    int d = idx & 63;
    int t = idx >> 6;
    int h = t % nh;
    int bs = t / nh;
    if (bs >= B_ * S_) return;
    int s = bs & (S_ - 1);
    float p = (float)pos[s];
    // inv_freq = 500000^(-d/64)
    float inv = expf(-(float)d * (1.0f / 64.0f) * 13.122363377404329f);
    float ang = p * inv;
    float c = cosf(ang), sn = sinf(ang);
    size_t off = (size_t)bs * rowstride + (size_t)h * D_;
    float x1 = (float)qk[off + d];
    float x2 = (float)qk[off + d + 64];
    qk[off + d]      = (__bf16)(x1 * c - x2 * sn);
    qk[off + d + 64] = (__bf16)(x2 * c + x1 * sn);
}

// ---------------- GEMM: C[M,N] = A[M,K] * B[N,K]^T, bf16 in, fp32 acc --------
// EPI 0: fp32 row-major C.  EPI 1: bf16 row-major C.
// EPI 2: fused KV epilogue: col<1024 -> bf16 row-major into Cv (ld=1024);
//        col>=1024 -> bf16 V^T into Cv2: vt[((b*KV+kv)*D+d)*S + s]
template <int EPI>
__global__ __launch_bounds__(256) void gemm_bt(
        const __bf16* __restrict__ A, const __bf16* __restrict__ Bm,
        void* __restrict__ Cv, void* __restrict__ Cv2, int M, int N, int K) {
    __shared__ __bf16 As[128 * 32];  // [m][k] row-major, 64B rows
    __shared__ __bf16 Bs[128 * 32];  // [n][k]
    const int tid  = threadIdx.x;
    const int wave = tid >> 6;
    const int lane = tid & 63;
    const int bm = blockIdx.y * 128;
    const int bn = blockIdx.x * 128;
    const int wm = (wave & 1) * 64;
    const int wn = (wave >> 1) * 64;
    const int l15  = lane & 15;
    const int quad = lane >> 4;

    v4f acc[4][4] = {};

    const int lm = lane >> 2;        // 0..15
    const int lk = (lane & 3) * 8;   // 0,8,16,24

    for (int k0 = 0; k0 < K; k0 += 32) {
        load_lds16(A  + (size_t)(bm +      wave * 16 + lm) * K + k0 + lk, (char*)As + (size_t)wave * 1024);
        load_lds16(A  + (size_t)(bm + 64 + wave * 16 + lm) * K + k0 + lk, (char*)As + (size_t)(4 + wave) * 1024);
        load_lds16(Bm + (size_t)(bn +      wave * 16 + lm) * K + k0 + lk, (char*)Bs + (size_t)wave * 1024);
        load_lds16(Bm + (size_t)(bn + 64 + wave * 16 + lm) * K + k0 + lk, (char*)Bs + (size_t)(4 + wave) * 1024);
        __syncthreads();

        v8bf af[4], bf[4];
        const int kq = quad * 8;
#pragma unroll
        for (int i = 0; i < 4; ++i)
            af[i] = *(const v8bf*)&As[(wm + i * 16 + l15) * 32 + kq];
#pragma unroll
        for (int j = 0; j < 4; ++j)
            bf[j] = *(const v8bf*)&Bs[(wn + j * 16 + l15) * 32 + kq];
#pragma unroll
        for (int i = 0; i < 4; ++i)
#pragma unroll
            for (int j = 0; j < 4; ++j)
                acc[i][j] = mfma16(af[i], bf[j], acc[i][j]);
        __syncthreads();
    }

    // epilogue: C/D layout col = lane&15, row = quad*4 + r  (m89/m91 verified)
#pragma unroll
    for (int i = 0; i < 4; ++i) {
#pragma unroll
        for (int j = 0; j < 4; ++j) {
#pragma unroll
            for (int r = 0; r < 4; ++r) {
                int row = bm + wm + i * 16 + quad * 4 + r;
                int col = bn + wn + j * 16 + l15;
                float val = acc[i][j][r];
                if (EPI == 0) {
                    ((float*)Cv)[(size_t)row * N + col] = val;
                } else if (EPI == 1) {
                    ((__bf16*)Cv)[(size_t)row * N + col] = (__bf16)val;
                } else {
                    if (col < 1024) {
                        ((__bf16*)Cv)[(size_t)row * 1024 + col] = (__bf16)val;
                    } else {
                        int cc = col - 1024;
                        int b  = row >> 11, s = row & (S_ - 1);
                        int kv = cc >> 7,  d = cc & (D_ - 1);
                        ((__bf16*)Cv2)[((size_t)((b * KV_ + kv) * D_ + d)) * S_ + s] = (__bf16)val;
                    }
                }
            }
        }
    }
}

// ---------------- fused causal flash attention (block-cooperative) ----------
// q: (B,S,E) bf16 roped; k: (B,S,KV*D) bf16 roped; vt: (B,KV,D,S) bf16
// Block = 4 waves = 64 queries of one (b,h). Per 64-key tile the block DMAs
// K-tile (64x128, 16KB) and V^T-tile (128x64, 16KB) into LDS with an XOR
// chunk swizzle (global source permuted per lane; LDS dest = base+lane*16).
// Waves then feed MFMA B-fragments from LDS (bank-balanced b128 reads).
__global__ __launch_bounds__(256, 4) void attn_fused(
        const __bf16* __restrict__ q, const __bf16* __restrict__ k,
        const __bf16* __restrict__ vt, __bf16* __restrict__ attn) {
    __shared__ __bf16 Ks[64 * 128];   // [key][d], chunk16 c at position c^(key&15)
    __shared__ __bf16 Vs[128 * 64];   // [d][key], chunk16 c at position c^(d&7)
    __shared__ __bf16 P[4][16 * 64];  // per-wave P tile [16 q][64 keys]
    const int wave = threadIdx.x >> 6;
    const int lane = threadIdx.x & 63;
    const int bh = blockIdx.y;
    const int b = bh >> 5;       // H=32
    const int h = bh & 31;
    const int kvh = h >> 2;      // rep = H/KV = 4
    const int qblk = (int)gridDim.x - 1 - (int)blockIdx.x;  // long blocks first
    const int q0 = qblk * 64 + wave * 16;
    const int l15  = lane & 15;
    const int quad = lane >> 4;

    const __bf16* qbase = q  + (size_t)(b * S_) * E_ + (size_t)h * D_;
    const __bf16* kbase = k  + (size_t)(b * S_) * (KV_ * D_) + (size_t)kvh * D_;
    const __bf16* vbase = vt + (size_t)((b * KV_ + kvh) * D_) * S_;
    __bf16* Pw = &P[wave][0];

    v8bf aq[4];
#pragma unroll
    for (int kc = 0; kc < 4; ++kc)
        aq[kc] = *(const v8bf*)(qbase + (size_t)(q0 + l15) * E_ + kc * 32 + quad * 8);

    v4f o[8] = {};
    float m_i[4], l_i[4];
#pragma unroll
    for (int r = 0; r < 4; ++r) { m_i[r] = -INFINITY; l_i[r] = 0.f; }

    const int ntiles = qblk + 1;               // block-uniform
    const int rowbase = q0 + quad * 4;
    const float scale = 0.08838834764831845f;  // 1/sqrt(128)

    const int krow_l = lane >> 4;   // 0..3   (K staging row within group)
    const int kcc    = lane & 15;   //        (K staging chunk)
    const int vrow_l = lane >> 3;   // 0..7   (V staging row within group)
    const int vcc    = lane & 7;    //        (V staging chunk)

    for (int t = 0; t < ntiles; ++t) {
        const int n0 = t * 64;

        // ---- stage K-tile + V^T-tile, swizzled, 8 DMA instrs per wave ----
#pragma unroll
        for (int i = 0; i < 4; ++i) {
            int g = wave * 4 + i;           // 0..15, 1KB each
            int row = g * 4 + krow_l;       // key 0..63
            int scc = kcc ^ (row & 15);
            load_lds16(kbase + (size_t)(n0 + row) * (KV_ * D_) + scc * 8,
                       (char*)Ks + (size_t)g * 1024);
        }
#pragma unroll
        for (int i = 0; i < 4; ++i) {
            int g = wave * 4 + i;           // 0..15, 1KB each
            int row = g * 8 + vrow_l;       // d 0..127
            int scc = vcc ^ (row & 7);
            load_lds16(vbase + (size_t)row * S_ + n0 + scc * 8,
                       (char*)Vs + (size_t)g * 1024);
        }
        __syncthreads();

        // ---- QK^T: 16 queries x 64 keys, K from LDS ----
        v4f s[4] = {};
#pragma unroll
        for (int kc = 0; kc < 4; ++kc) {
            v8bf kf[4];
#pragma unroll
            for (int j = 0; j < 4; ++j)
                kf[j] = *(const v8bf*)&Ks[(j * 16 + l15) * 128 +
                                          (((kc * 4 + quad) ^ l15) * 8)];
#pragma unroll
            for (int j = 0; j < 4; ++j)
                s[j] = mfma16(aq[kc], kf[j], s[j]);
        }

        // ---- scale + (boundary-only) causal mask ----
        float e[4][4];
        if (n0 + 63 > q0) {           // wave-uniform
#pragma unroll
            for (int j = 0; j < 4; ++j)
#pragma unroll
                for (int r = 0; r < 4; ++r) {
                    float v = s[j][r] * scale;
                    if (n0 + j * 16 + l15 > rowbase + r) v = -INFINITY;
                    e[j][r] = v;
                }
        } else {
#pragma unroll
            for (int j = 0; j < 4; ++j)
#pragma unroll
                for (int r = 0; r < 4; ++r)
                    e[j][r] = s[j][r] * scale;
        }

        // ---- online softmax (row = 16 l15-lanes within each quad) ----
        float mloc[4];
#pragma unroll
        for (int r = 0; r < 4; ++r)
            mloc[r] = fmaxf(fmaxf(e[0][r], e[1][r]), fmaxf(e[2][r], e[3][r]));
#pragma unroll
        for (int off = 1; off < 16; off <<= 1)
#pragma unroll
            for (int r = 0; r < 4; ++r)
                mloc[r] = fmaxf(mloc[r], __shfl_xor(mloc[r], off, 64));

        float alpha[4], psum[4];
#pragma unroll
        for (int r = 0; r < 4; ++r) {
            float mnew = fmaxf(m_i[r], mloc[r]);
            alpha[r] = __expf(m_i[r] - mnew);   // exp(-inf)=0 on first tile
            m_i[r] = mnew;
#pragma unroll
            for (int j = 0; j < 4; ++j)
                e[j][r] = __expf(e[j][r] - mnew);
            psum[r] = (e[0][r] + e[1][r]) + (e[2][r] + e[3][r]);
        }
#pragma unroll
        for (int off = 1; off < 16; off <<= 1)
#pragma unroll
            for (int r = 0; r < 4; ++r)
                psum[r] += __shfl_xor(psum[r], off, 64);
#pragma unroll
        for (int r = 0; r < 4; ++r)
            l_i[r] = l_i[r] * alpha[r] + psum[r];
#pragma unroll
        for (int c = 0; c < 8; ++c)
#pragma unroll
            for (int r = 0; r < 4; ++r)
                o[c][r] *= alpha[r];

        // ---- P: C-layout -> wave-private LDS [16 rows][64 cols] ----
#pragma unroll
        for (int j = 0; j < 4; ++j)
#pragma unroll
            for (int r = 0; r < 4; ++r)
                Pw[(quad * 4 + r) * 64 + j * 16 + l15] = (__bf16)e[j][r];

        // re-read as A-fragment: A[m=l15][k=quad*8+i] per 32-key chunk
        v8bf ap0 = *(const v8bf*)&Pw[l15 * 64 + quad * 8];
        v8bf ap1 = *(const v8bf*)&Pw[l15 * 64 + 32 + quad * 8];

        // ---- PV: o[d-tile] += P * V^T, V from LDS ----
#pragma unroll
        for (int c = 0; c < 8; ++c) {
            v8bf v0 = *(const v8bf*)&Vs[(c * 16 + l15) * 64 +
                                        ((quad ^ (l15 & 7)) * 8)];
            v8bf v1 = *(const v8bf*)&Vs[(c * 16 + l15) * 64 +
                                        (((4 + quad) ^ (l15 & 7)) * 8)];
            o[c] = mfma16(ap0, v0, o[c]);
            o[c] = mfma16(ap1, v1, o[c]);
        }
        __syncthreads();   // all waves done with Ks/Vs before next DMA
    }

    float linv[4];
#pragma unroll
    for (int r = 0; r < 4; ++r) linv[r] = 1.0f / l_i[r];
    __bf16* obase = attn + (size_t)(b * S_) * E_ + (size_t)h * D_;
#pragma unroll
    for (int c = 0; c < 8; ++c)
#pragma unroll
        for (int r = 0; r < 4; ++r)
            obase[(size_t)(q0 + quad * 4 + r) * E_ + c * 16 + l15] =
                (__bf16)(o[c][r] * linv[r]);
}

extern "C" void kernel_launch(void* const* d_in, const int* in_sizes, int n_in,
                              void* d_out, int out_size, void* d_ws, size_t ws_size,
                              hipStream_t stream) {
    (void)in_sizes; (void)n_in; (void)out_size; (void)ws_size;
    const float* x  = (const float*)d_in[0];
    const float* wq = (const float*)d_in[1];
    const float* wk = (const float*)d_in[2];
    const float* wv = (const float*)d_in[3];
    const float* wo = (const float*)d_in[4];
    const int*   pos = (const int*)d_in[5];
    float* out = (float*)d_out;

    char* ws = (char*)d_ws;
    size_t off = 0;
    auto alloc = [&](size_t bytes) {
        char* p = ws + off;
        off += (bytes + 255) & ~(size_t)255;
        return p;
    };
    __bf16* xb   = (__bf16*)alloc((size_t)B_ * S_ * E_ * 2);
    __bf16* wqb  = (__bf16*)alloc((size_t)E_ * E_ * 2);
    __bf16* wkvb = (__bf16*)alloc((size_t)2 * KV_ * D_ * E_ * 2);  // [wk;wv] rows
    __bf16* wob  = (__bf16*)alloc((size_t)E_ * E_ * 2);
    __bf16* qb   = (__bf16*)alloc((size_t)B_ * S_ * E_ * 2);
    __bf16* kb   = (__bf16*)alloc((size_t)B_ * S_ * KV_ * D_ * 2);
    __bf16* vt   = (__bf16*)alloc((size_t)B_ * KV_ * D_ * S_ * 2);
    __bf16* at   = (__bf16*)alloc((size_t)B_ * S_ * E_ * 2);

    auto cast = [&](const float* in, __bf16* ob, size_t n) {
        int n4 = (int)(n / 4);
        cast_f32_to_bf16<<<(n4 + 255) / 256, 256, 0, stream>>>(
            (const float4*)in, (v4bf*)ob, n4);
    };
    cast(x,  xb,  (size_t)B_ * S_ * E_);
    cast(wq, wqb, (size_t)E_ * E_);
    cast(wk, wkvb, (size_t)KV_ * D_ * E_);
    cast(wv, wkvb + (size_t)KV_ * D_ * E_, (size_t)KV_ * D_ * E_);
    cast(wo, wob, (size_t)E_ * E_);

    const int M = B_ * S_;
    gemm_bt<1><<<dim3(E_ / 128, M / 128), 256, 0, stream>>>(
        xb, wqb, qb, nullptr, M, E_, E_);
    gemm_bt<2><<<dim3(2 * KV_ * D_ / 128, M / 128), 256, 0, stream>>>(
        xb, wkvb, kb, vt, M, 2 * KV_ * D_, E_);

    rope_inplace<<<(B_ * S_ * H_ * 64 + 255) / 256, 256, 0, stream>>>(qb, pos, H_, E_);
    rope_inplace<<<(B_ * S_ * KV_ * 64 + 255) / 256, 256, 0, stream>>>(kb, pos, KV_, KV_ * D_);

    attn_fused<<<dim3(S_ / 64, B_ * H_), 256, 0, stream>>>(qb, kb, vt, at);

    gemm_bt<0><<<dim3(E_ / 128, M / 128), 256, 0, stream>>>(
        at, wob, out, nullptr, M, E_, E_);
}